// Round 1
// baseline (898.733 us; speedup 1.0000x reference)
//
#include <hip/hip_runtime.h>
#include <hip/hip_bf16.h>
#include <cstdint>
#include <cstddef>

#define NNODES 50000
#define NEDGES 800000
#define D_IN   128
#define D_H    256
#define D_OUT  64

// ---------------- CSR build ----------------

__global__ void k_hist(const int* __restrict__ dst, int* __restrict__ cnt, int e) {
    int i = blockIdx.x * blockDim.x + threadIdx.x;
    if (i < e) atomicAdd(&cnt[dst[i]], 1);
}

__global__ __launch_bounds__(1024) void k_scan(const int* __restrict__ cnt, int* __restrict__ rp, int n) {
    __shared__ int s[1024];
    __shared__ int carry_s;
    int tid = threadIdx.x;
    if (tid == 0) carry_s = 0;
    __syncthreads();
    for (int base = 0; base < n; base += 1024) {
        int i = base + tid;
        int v = (i < n) ? cnt[i] : 0;
        int sum = v;
        s[tid] = v;
        __syncthreads();
        #pragma unroll
        for (int off = 1; off < 1024; off <<= 1) {
            int t = (tid >= off) ? s[tid - off] : 0;
            __syncthreads();
            sum += t;
            s[tid] = sum;
            __syncthreads();
        }
        int carry = carry_s;
        if (i < n) rp[i] = carry + sum - v;  // exclusive
        __syncthreads();
        if (tid == 1023) carry_s = carry + s[1023];
        __syncthreads();
    }
    if (tid == 0) rp[n] = carry_s;
}

__global__ void k_dinv(const int* __restrict__ cnt, float* __restrict__ dinv, int n) {
    int i = blockIdx.x * blockDim.x + threadIdx.x;
    if (i < n) dinv[i] = rsqrtf((float)(cnt[i] + 1));  // +1 self loop, deg>=1
}

__global__ void k_scatter(const int* __restrict__ src, const int* __restrict__ dst,
                          const int* __restrict__ rp, int* __restrict__ cur,
                          int* __restrict__ col, int e) {
    int i = blockIdx.x * blockDim.x + threadIdx.x;
    if (i < e) {
        int d = dst[i];
        int p = rp[d] + atomicAdd(&cur[d], 1);
        col[p] = src[i];
    }
}

// ---------------- Aggregation: out[i] = dinv[i]*(sum_j dinv[j]*h[j] + dinv[i]*h[i]) (+bias) ----------------

template<int F, bool ADD_BIAS>
__global__ __launch_bounds__(256) void k_agg(const float* __restrict__ h, const int* __restrict__ rp,
                                             const int* __restrict__ col, const float* __restrict__ dinv,
                                             const float* __restrict__ bias, float* __restrict__ out, int n) {
    constexpr int VPT = F / 64;
    int wave = threadIdx.x >> 6;
    int lane = threadIdx.x & 63;
    int i = blockIdx.x * 4 + wave;
    if (i >= n) return;
    float acc[VPT];
    #pragma unroll
    for (int c = 0; c < VPT; ++c) acc[c] = 0.f;
    int beg = rp[i], end = rp[i + 1];
    for (int k = beg; k < end; ++k) {
        int j = col[k];
        float w = dinv[j];
        const float* hj = h + (size_t)j * F + lane * VPT;
        if constexpr (VPT == 4) {
            float4 v = *(const float4*)hj;
            acc[0] += v.x * w; acc[1] += v.y * w; acc[2] += v.z * w; acc[3] += v.w * w;
        } else if constexpr (VPT == 2) {
            float2 v = *(const float2*)hj;
            acc[0] += v.x * w; acc[1] += v.y * w;
        } else {
            acc[0] += *hj * w;
        }
    }
    float di = dinv[i];
    const float* hi = h + (size_t)i * F + lane * VPT;
    if constexpr (VPT == 4) {
        float4 v = *(const float4*)hi;
        acc[0] += v.x * di; acc[1] += v.y * di; acc[2] += v.z * di; acc[3] += v.w * di;
    } else if constexpr (VPT == 2) {
        float2 v = *(const float2*)hi;
        acc[0] += v.x * di; acc[1] += v.y * di;
    } else {
        acc[0] += *hi * di;
    }
    float* op = out + (size_t)i * F + lane * VPT;
    if constexpr (VPT == 4) {
        float4 o;
        o.x = acc[0] * di; o.y = acc[1] * di; o.z = acc[2] * di; o.w = acc[3] * di;
        if constexpr (ADD_BIAS) {
            const float4 b = *(const float4*)(bias + lane * 4);
            o.x += b.x; o.y += b.y; o.z += b.z; o.w += b.w;
        }
        *(float4*)op = o;
    } else if constexpr (VPT == 2) {
        float2 o;
        o.x = acc[0] * di; o.y = acc[1] * di;
        if constexpr (ADD_BIAS) {
            const float2 b = *(const float2*)(bias + lane * 2);
            o.x += b.x; o.y += b.y;
        }
        *(float2*)op = o;
    } else {
        float o = acc[0] * di;
        if constexpr (ADD_BIAS) o += bias[lane];
        *op = o;
    }
}

// ---------------- fp32 GEMM: C[M,Nc] = A[M,K] @ B[K,Nc] (+bias, relu) ----------------
// 64x64 tile per 256-thread block, BK=64, A staged transposed in LDS.

template<bool RELU, bool BIAS>
__global__ __launch_bounds__(256) void k_gemm(const float* __restrict__ A, const float* __restrict__ B,
                                              const float* __restrict__ bias, float* __restrict__ C,
                                              int M, int K, int Nc) {
    __shared__ float As[64][68];   // As[k][m], pad 68 -> conflict-free b128 reads
    __shared__ float Bs[64][64];   // Bs[k][c]
    int tid = threadIdx.x;
    int row0 = blockIdx.x * 64;
    int col0 = blockIdx.y * 64;
    int tx = tid & 15, ty = tid >> 4;
    float acc[4][4];
    #pragma unroll
    for (int i = 0; i < 4; ++i)
        #pragma unroll
        for (int j = 0; j < 4; ++j) acc[i][j] = 0.f;

    for (int kt = 0; kt < K; kt += 64) {
        // stage A tile (64 rows x 64 k) transposed
        #pragma unroll
        for (int p = 0; p < 4; ++p) {
            int m = (tid >> 4) + p * 16;
            int kq = (tid & 15);
            int row = row0 + m;
            if (row >= M) row = M - 1;  // safe read; store guarded later
            float4 v = *(const float4*)(A + (size_t)row * K + kt + kq * 4);
            As[kq * 4 + 0][m] = v.x;
            As[kq * 4 + 1][m] = v.y;
            As[kq * 4 + 2][m] = v.z;
            As[kq * 4 + 3][m] = v.w;
        }
        // stage B tile (64 k x 64 cols)
        #pragma unroll
        for (int p = 0; p < 4; ++p) {
            int k = (tid >> 4) + p * 16;
            int c = (tid & 15) * 4;
            float4 v = *(const float4*)(B + (size_t)(kt + k) * Nc + col0 + c);
            *(float4*)&Bs[k][c] = v;
        }
        __syncthreads();
        #pragma unroll 8
        for (int k = 0; k < 64; ++k) {
            float4 a4 = *(const float4*)&As[k][ty * 4];
            float4 b4 = *(const float4*)&Bs[k][tx * 4];
            acc[0][0] += a4.x * b4.x; acc[0][1] += a4.x * b4.y; acc[0][2] += a4.x * b4.z; acc[0][3] += a4.x * b4.w;
            acc[1][0] += a4.y * b4.x; acc[1][1] += a4.y * b4.y; acc[1][2] += a4.y * b4.z; acc[1][3] += a4.y * b4.w;
            acc[2][0] += a4.z * b4.x; acc[2][1] += a4.z * b4.y; acc[2][2] += a4.z * b4.z; acc[2][3] += a4.z * b4.w;
            acc[3][0] += a4.w * b4.x; acc[3][1] += a4.w * b4.y; acc[3][2] += a4.w * b4.z; acc[3][3] += a4.w * b4.w;
        }
        __syncthreads();
    }

    float4 bv = {0.f, 0.f, 0.f, 0.f};
    if constexpr (BIAS) bv = *(const float4*)(bias + col0 + tx * 4);
    #pragma unroll
    for (int i = 0; i < 4; ++i) {
        int row = row0 + ty * 4 + i;
        if (row < M) {
            float4 o;
            o.x = acc[i][0] + bv.x;
            o.y = acc[i][1] + bv.y;
            o.z = acc[i][2] + bv.z;
            o.w = acc[i][3] + bv.w;
            if constexpr (RELU) {
                o.x = fmaxf(o.x, 0.f); o.y = fmaxf(o.y, 0.f);
                o.z = fmaxf(o.z, 0.f); o.w = fmaxf(o.w, 0.f);
            }
            *(float4*)(C + (size_t)row * Nc + col0 + tx * 4) = o;
        }
    }
}

// ---------------- conditional softmax over 64 classes ----------------

__global__ __launch_bounds__(256) void k_softmax(float* __restrict__ out, const int* __restrict__ mode, int n) {
    if (*mode == 1) return;
    int wave = threadIdx.x >> 6;
    int lane = threadIdx.x & 63;
    int i = blockIdx.x * 4 + wave;
    if (i >= n) return;
    float v = out[(size_t)i * 64 + lane];
    float m = v;
    #pragma unroll
    for (int off = 32; off > 0; off >>= 1) m = fmaxf(m, __shfl_xor(m, off));
    float e = __expf(v - m);
    float s = e;
    #pragma unroll
    for (int off = 32; off > 0; off >>= 1) s += __shfl_xor(s, off);
    out[(size_t)i * 64 + lane] = e / s;
}

// ---------------- launch ----------------

extern "C" void kernel_launch(void* const* d_in, const int* in_sizes, int n_in,
                              void* d_out, int out_size, void* d_ws, size_t ws_size,
                              hipStream_t stream) {
    const float* x   = (const float*)d_in[0];
    const float* W1  = (const float*)d_in[1];
    const float* b1  = (const float*)d_in[2];
    const float* W2  = (const float*)d_in[3];
    const float* b2  = (const float*)d_in[4];
    const float* L1w = (const float*)d_in[5];
    const float* L1b = (const float*)d_in[6];
    const float* L2w = (const float*)d_in[7];
    const float* L2b = (const float*)d_in[8];
    const float* W3  = (const float*)d_in[9];
    const float* b3  = (const float*)d_in[10];
    const int* adj   = (const int*)d_in[11];
    const int* adj2  = (const int*)d_in[12];
    const int* mode  = (const int*)d_in[13];
    float* out = (float*)d_out;

    char* ws = (char*)d_ws;
    auto alloc = [&](size_t bytes) {
        char* p = ws;
        ws += (bytes + 255) & ~(size_t)255;
        return p;
    };
    float* bufA  = (float*)alloc((size_t)NNODES * 256 * 4);
    float* bufB  = (float*)alloc((size_t)NNODES * 256 * 4);
    int*   rp1   = (int*)alloc((NNODES + 1) * 4);
    int*   col1  = (int*)alloc((size_t)NEDGES * 4);
    int*   rp2   = (int*)alloc((NNODES + 1) * 4);
    int*   col2  = (int*)alloc((size_t)NEDGES * 4);
    float* dinv1 = (float*)alloc(NNODES * 4);
    float* dinv2 = (float*)alloc(NNODES * 4);
    int*   tmp   = (int*)alloc(NNODES * 4);

    const int EB = (NEDGES + 255) / 256;
    const int NB = (NNODES + 255) / 256;
    const int AGB = (NNODES + 3) / 4;
    const int MT = (NNODES + 63) / 64;

    // build CSR for adj (graph 1)
    hipMemsetAsync(tmp, 0, NNODES * 4, stream);
    k_hist<<<EB, 256, 0, stream>>>(adj + NEDGES, tmp, NEDGES);
    k_scan<<<1, 1024, 0, stream>>>(tmp, rp1, NNODES);
    k_dinv<<<NB, 256, 0, stream>>>(tmp, dinv1, NNODES);
    hipMemsetAsync(tmp, 0, NNODES * 4, stream);
    k_scatter<<<EB, 256, 0, stream>>>(adj, adj + NEDGES, rp1, tmp, col1, NEDGES);

    // build CSR for adj2 (graph 2)
    hipMemsetAsync(tmp, 0, NNODES * 4, stream);
    k_hist<<<EB, 256, 0, stream>>>(adj2 + NEDGES, tmp, NEDGES);
    k_scan<<<1, 1024, 0, stream>>>(tmp, rp2, NNODES);
    k_dinv<<<NB, 256, 0, stream>>>(tmp, dinv2, NNODES);
    hipMemsetAsync(tmp, 0, NNODES * 4, stream);
    k_scatter<<<EB, 256, 0, stream>>>(adj2, adj2 + NEDGES, rp2, tmp, col2, NEDGES);

    // conv1: h1 = relu((A1 x) W1 + b1)
    k_agg<128, false><<<AGB, 256, 0, stream>>>(x, rp1, col1, dinv1, nullptr, bufA, NNODES);
    k_gemm<true, true><<<dim3(MT, D_H / 64), 256, 0, stream>>>(bufA, W1, b1, bufB, NNODES, D_IN, D_H);
    // conv2: h2 = relu((A2 h1) W2 + b2)
    k_agg<256, false><<<AGB, 256, 0, stream>>>(bufB, rp2, col2, dinv2, nullptr, bufA, NNODES);
    k_gemm<true, true><<<dim3(MT, D_H / 64), 256, 0, stream>>>(bufA, W2, b2, bufB, NNODES, D_H, D_H);
    // h3 = relu(h2 L1w + L1b)
    k_gemm<true, true><<<dim3(MT, D_IN / 64), 256, 0, stream>>>(bufB, L1w, L1b, bufA, NNODES, D_H, D_IN);
    // h4 = relu(h3 L2w + L2b)
    k_gemm<true, true><<<dim3(MT, D_H / 64), 256, 0, stream>>>(bufA, L2w, L2b, bufB, NNODES, D_IN, D_H);
    // conv3: out = A2 (h4 W3) + b3
    k_gemm<false, false><<<dim3(MT, D_OUT / 64), 256, 0, stream>>>(bufB, W3, nullptr, bufA, NNODES, D_H, D_OUT);
    k_agg<64, true><<<AGB, 256, 0, stream>>>(bufA, rp2, col2, dinv2, b3, out, NNODES);
    // optional softmax (mode != 1) — self-disables for mode==1
    k_softmax<<<AGB, 256, 0, stream>>>(out, mode, NNODES);
}

// Round 2
// 830.626 us; speedup vs baseline: 1.0820x; 1.0820x over previous
//
#include <hip/hip_runtime.h>
#include <hip/hip_bf16.h>
#include <cstdint>
#include <cstddef>

#define NNODES 50000
#define NEDGES 800000
#define D_IN   128
#define D_H    256
#define D_OUT  64

typedef __attribute__((ext_vector_type(8))) short bf16x8;
typedef __attribute__((ext_vector_type(4))) float f32x4;

__device__ __forceinline__ unsigned short f2bf(float f) {
    unsigned u = __builtin_bit_cast(unsigned, f);
    unsigned r = (u + 0x7FFFu + ((u >> 16) & 1u)) >> 16;
    return (unsigned short)r;
}
__device__ __forceinline__ float bf2f(unsigned short h) {
    unsigned u = ((unsigned)h) << 16;
    return __builtin_bit_cast(float, u);
}

// ---------------- CSR build ----------------

__global__ void k_hist(const int* __restrict__ dst, int* __restrict__ cnt, int e) {
    int i = blockIdx.x * blockDim.x + threadIdx.x;
    if (i < e) atomicAdd(&cnt[dst[i]], 1);
}

__global__ __launch_bounds__(1024) void k_scan(const int* __restrict__ cnt, int* __restrict__ rp, int n) {
    __shared__ int s[1024];
    __shared__ int carry_s;
    int tid = threadIdx.x;
    if (tid == 0) carry_s = 0;
    __syncthreads();
    for (int base = 0; base < n; base += 1024) {
        int i = base + tid;
        int v = (i < n) ? cnt[i] : 0;
        int sum = v;
        s[tid] = v;
        __syncthreads();
        #pragma unroll
        for (int off = 1; off < 1024; off <<= 1) {
            int t = (tid >= off) ? s[tid - off] : 0;
            __syncthreads();
            sum += t;
            s[tid] = sum;
            __syncthreads();
        }
        int carry = carry_s;
        if (i < n) rp[i] = carry + sum - v;  // exclusive
        __syncthreads();
        if (tid == 1023) carry_s = carry + s[1023];
        __syncthreads();
    }
    if (tid == 0) rp[n] = carry_s;
}

__global__ void k_dinv(const int* __restrict__ cnt, float* __restrict__ dinv, int n) {
    int i = blockIdx.x * blockDim.x + threadIdx.x;
    if (i < n) dinv[i] = rsqrtf((float)(cnt[i] + 1));  // +1 self loop
}

__global__ void k_scatter(const int* __restrict__ src, const int* __restrict__ dst,
                          const int* __restrict__ rp, int* __restrict__ cur,
                          int* __restrict__ col, int e) {
    int i = blockIdx.x * blockDim.x + threadIdx.x;
    if (i < e) {
        int d = dst[i];
        int p = rp[d] + atomicAdd(&cur[d], 1);
        col[p] = src[i];
    }
}

// ---------------- Aggregation ----------------

template<int F, bool ADD_BIAS>
__global__ __launch_bounds__(256) void k_agg(const float* __restrict__ h, const int* __restrict__ rp,
                                             const int* __restrict__ col, const float* __restrict__ dinv,
                                             const float* __restrict__ bias, float* __restrict__ out, int n) {
    constexpr int VPT = F / 64;
    int wave = threadIdx.x >> 6;
    int lane = threadIdx.x & 63;
    int i = blockIdx.x * 4 + wave;
    if (i >= n) return;
    float acc[VPT];
    #pragma unroll
    for (int c = 0; c < VPT; ++c) acc[c] = 0.f;
    int beg = rp[i], end = rp[i + 1];
    for (int k = beg; k < end; ++k) {
        int j = col[k];
        float w = dinv[j];
        const float* hj = h + (size_t)j * F + lane * VPT;
        if constexpr (VPT == 4) {
            float4 v = *(const float4*)hj;
            acc[0] += v.x * w; acc[1] += v.y * w; acc[2] += v.z * w; acc[3] += v.w * w;
        } else if constexpr (VPT == 2) {
            float2 v = *(const float2*)hj;
            acc[0] += v.x * w; acc[1] += v.y * w;
        } else {
            acc[0] += *hj * w;
        }
    }
    float di = dinv[i];
    const float* hi = h + (size_t)i * F + lane * VPT;
    if constexpr (VPT == 4) {
        float4 v = *(const float4*)hi;
        acc[0] += v.x * di; acc[1] += v.y * di; acc[2] += v.z * di; acc[3] += v.w * di;
    } else if constexpr (VPT == 2) {
        float2 v = *(const float2*)hi;
        acc[0] += v.x * di; acc[1] += v.y * di;
    } else {
        acc[0] += *hi * di;
    }
    float* op = out + (size_t)i * F + lane * VPT;
    if constexpr (VPT == 4) {
        float4 o;
        o.x = acc[0] * di; o.y = acc[1] * di; o.z = acc[2] * di; o.w = acc[3] * di;
        if constexpr (ADD_BIAS) {
            const float4 b = *(const float4*)(bias + lane * 4);
            o.x += b.x; o.y += b.y; o.z += b.z; o.w += b.w;
        }
        *(float4*)op = o;
    } else if constexpr (VPT == 2) {
        float2 o;
        o.x = acc[0] * di; o.y = acc[1] * di;
        if constexpr (ADD_BIAS) {
            const float2 b = *(const float2*)(bias + lane * 2);
            o.x += b.x; o.y += b.y;
        }
        *(float2*)op = o;
    } else {
        float o = acc[0] * di;
        if constexpr (ADD_BIAS) o += bias[lane];
        *op = o;
    }
}

// ---------------- weight preconvert: W[K][N] fp32 -> Bt_hi/Bt_lo [N][K] bf16 ----------------

__global__ void k_wconv(const float* __restrict__ W, unsigned short* __restrict__ Th,
                        unsigned short* __restrict__ Tl, int K, int Nc) {
    int idx = blockIdx.x * blockDim.x + threadIdx.x;
    if (idx >= K * Nc) return;
    int k = idx / Nc, n = idx - k * Nc;
    float v = W[idx];
    unsigned short h = f2bf(v);
    unsigned short l = f2bf(v - bf2f(h));
    Th[(size_t)n * K + k] = h;
    Tl[(size_t)n * K + k] = l;
}

// ---------------- MFMA GEMM (bf16x3 split-precision fp32 emulation) ----------------
// C[M,Nc] = A[M,K] @ B[K,Nc] (+bias, relu). Tile 128x64, BK=64, 4 waves.

template<bool RELU, bool BIAS>
__global__ __launch_bounds__(256) void k_gemm_mfma(const float* __restrict__ A,
        const unsigned short* __restrict__ Bth, const unsigned short* __restrict__ Btl,
        const float* __restrict__ bias, float* __restrict__ C, int M, int K, int Nc) {
    constexpr int PAD = 72;  // 144B row stride = 36 dwords -> 2-way bank alias (free)
    __shared__ unsigned short As_h[128][PAD];
    __shared__ unsigned short As_l[128][PAD];
    __shared__ unsigned short Bs_h[64][PAD];
    __shared__ unsigned short Bs_l[64][PAD];

    const int tid = threadIdx.x;
    const int lane = tid & 63;
    const int wv = tid >> 6;
    const int row0 = blockIdx.x * 128;
    const int col0 = blockIdx.y * 64;

    f32x4 acc[2][4];
    #pragma unroll
    for (int m = 0; m < 2; ++m)
        #pragma unroll
        for (int n = 0; n < 4; ++n) acc[m][n] = (f32x4)(0.f);

    // A staging: thread covers row srow, 32 k-values
    const int srow = tid >> 1;
    const int skh = (tid & 1) * 32;
    int arow = row0 + srow;
    if (arow >= M) arow = M - 1;  // safe clamp; C store is guarded
    const float* aptr = A + (size_t)arow * K + skh;

    // B staging: thread covers col bn, 16 k-values
    const int bn = tid >> 2;
    const int bko = (tid & 3) * 16;
    const unsigned short* bph = Bth + (size_t)(col0 + bn) * K + bko;
    const unsigned short* bpl = Btl + (size_t)(col0 + bn) * K + bko;

    const int fr = lane & 15;
    const int fk = (lane >> 4) * 8;

    const int nk = K >> 6;
    for (int kt = 0; kt < nk; ++kt) {
        float4 av[8];
        #pragma unroll
        for (int q = 0; q < 8; ++q)
            av[q] = *(const float4*)(aptr + kt * 64 + q * 4);
        uint4 bh0 = *(const uint4*)(bph + kt * 64);
        uint4 bh1 = *(const uint4*)(bph + kt * 64 + 8);
        uint4 bl0 = *(const uint4*)(bpl + kt * 64);
        uint4 bl1 = *(const uint4*)(bpl + kt * 64 + 8);

        __syncthreads();  // previous tile's reads complete

        #pragma unroll
        for (int q = 0; q < 8; ++q) {
            float4 v = av[q];
            unsigned short h0 = f2bf(v.x), h1 = f2bf(v.y), h2 = f2bf(v.z), h3 = f2bf(v.w);
            ushort4 hh; hh.x = h0; hh.y = h1; hh.z = h2; hh.w = h3;
            ushort4 ll;
            ll.x = f2bf(v.x - bf2f(h0));
            ll.y = f2bf(v.y - bf2f(h1));
            ll.z = f2bf(v.z - bf2f(h2));
            ll.w = f2bf(v.w - bf2f(h3));
            *(ushort4*)&As_h[srow][skh + q * 4] = hh;
            *(ushort4*)&As_l[srow][skh + q * 4] = ll;
        }
        *(uint4*)&Bs_h[bn][bko] = bh0;
        *(uint4*)&Bs_h[bn][bko + 8] = bh1;
        *(uint4*)&Bs_l[bn][bko] = bl0;
        *(uint4*)&Bs_l[bn][bko + 8] = bl1;

        __syncthreads();

        #pragma unroll
        for (int ks = 0; ks < 2; ++ks) {
            const int ko = ks * 32 + fk;
            bf16x8 ah[2], al[2], bh[4], bl[4];
            #pragma unroll
            for (int m = 0; m < 2; ++m) {
                ah[m] = *(const bf16x8*)&As_h[wv * 32 + m * 16 + fr][ko];
                al[m] = *(const bf16x8*)&As_l[wv * 32 + m * 16 + fr][ko];
            }
            #pragma unroll
            for (int n = 0; n < 4; ++n) {
                bh[n] = *(const bf16x8*)&Bs_h[n * 16 + fr][ko];
                bl[n] = *(const bf16x8*)&Bs_l[n * 16 + fr][ko];
            }
            #pragma unroll
            for (int m = 0; m < 2; ++m)
                #pragma unroll
                for (int n = 0; n < 4; ++n) {
                    acc[m][n] = __builtin_amdgcn_mfma_f32_16x16x32_bf16(ah[m], bh[n], acc[m][n], 0, 0, 0);
                    acc[m][n] = __builtin_amdgcn_mfma_f32_16x16x32_bf16(ah[m], bl[n], acc[m][n], 0, 0, 0);
                    acc[m][n] = __builtin_amdgcn_mfma_f32_16x16x32_bf16(al[m], bh[n], acc[m][n], 0, 0, 0);
                }
        }
    }

    // epilogue: D col = lane&15, row = (lane>>4)*4 + j
    const int rbase = row0 + wv * 32 + (lane >> 4) * 4;
    #pragma unroll
    for (int n = 0; n < 4; ++n) {
        const int c = col0 + n * 16 + fr;
        float bv = 0.f;
        if constexpr (BIAS) bv = bias[c];
        #pragma unroll
        for (int m = 0; m < 2; ++m) {
            #pragma unroll
            for (int j = 0; j < 4; ++j) {
                int r = rbase + m * 16 + j;
                if (r < M) {
                    float o = acc[m][n][j] + bv;
                    if constexpr (RELU) o = fmaxf(o, 0.f);
                    C[(size_t)r * Nc + c] = o;
                }
            }
        }
    }
}

// ---------------- conditional softmax over 64 classes ----------------

__global__ __launch_bounds__(256) void k_softmax(float* __restrict__ out, const int* __restrict__ mode, int n) {
    if (*mode == 1) return;
    int wave = threadIdx.x >> 6;
    int lane = threadIdx.x & 63;
    int i = blockIdx.x * 4 + wave;
    if (i >= n) return;
    float v = out[(size_t)i * 64 + lane];
    float m = v;
    #pragma unroll
    for (int off = 32; off > 0; off >>= 1) m = fmaxf(m, __shfl_xor(m, off));
    float e = __expf(v - m);
    float s = e;
    #pragma unroll
    for (int off = 32; off > 0; off >>= 1) s += __shfl_xor(s, off);
    out[(size_t)i * 64 + lane] = e / s;
}

// ---------------- launch ----------------

extern "C" void kernel_launch(void* const* d_in, const int* in_sizes, int n_in,
                              void* d_out, int out_size, void* d_ws, size_t ws_size,
                              hipStream_t stream) {
    const float* x   = (const float*)d_in[0];
    const float* W1  = (const float*)d_in[1];
    const float* b1  = (const float*)d_in[2];
    const float* W2  = (const float*)d_in[3];
    const float* b2  = (const float*)d_in[4];
    const float* L1w = (const float*)d_in[5];
    const float* L1b = (const float*)d_in[6];
    const float* L2w = (const float*)d_in[7];
    const float* L2b = (const float*)d_in[8];
    const float* W3  = (const float*)d_in[9];
    const float* b3  = (const float*)d_in[10];
    const int* adj   = (const int*)d_in[11];
    const int* adj2  = (const int*)d_in[12];
    const int* mode  = (const int*)d_in[13];
    float* out = (float*)d_out;

    char* ws = (char*)d_ws;
    auto alloc = [&](size_t bytes) {
        char* p = ws;
        ws += (bytes + 255) & ~(size_t)255;
        return p;
    };
    float* bufA  = (float*)alloc((size_t)NNODES * 256 * 4);
    float* bufB  = (float*)alloc((size_t)NNODES * 256 * 4);
    int*   rp1   = (int*)alloc((NNODES + 1) * 4);
    int*   col1  = (int*)alloc((size_t)NEDGES * 4);
    int*   rp2   = (int*)alloc((NNODES + 1) * 4);
    int*   col2  = (int*)alloc((size_t)NEDGES * 4);
    float* dinv1 = (float*)alloc(NNODES * 4);
    float* dinv2 = (float*)alloc(NNODES * 4);
    int*   tmp   = (int*)alloc(NNODES * 4);
    // bf16 hi/lo transposed weights
    unsigned short* W1h = (unsigned short*)alloc(D_IN * D_H * 2);
    unsigned short* W1l = (unsigned short*)alloc(D_IN * D_H * 2);
    unsigned short* W2h = (unsigned short*)alloc(D_H * D_H * 2);
    unsigned short* W2l = (unsigned short*)alloc(D_H * D_H * 2);
    unsigned short* L1h = (unsigned short*)alloc(D_H * D_IN * 2);
    unsigned short* L1l = (unsigned short*)alloc(D_H * D_IN * 2);
    unsigned short* L2h = (unsigned short*)alloc(D_IN * D_H * 2);
    unsigned short* L2l = (unsigned short*)alloc(D_IN * D_H * 2);
    unsigned short* W3h = (unsigned short*)alloc(D_H * D_OUT * 2);
    unsigned short* W3l = (unsigned short*)alloc(D_H * D_OUT * 2);

    const int EB = (NEDGES + 255) / 256;
    const int NB = (NNODES + 255) / 256;
    const int AGB = (NNODES + 3) / 4;
    const int MT = (NNODES + 127) / 128;

    // weight conversion (tiny)
    k_wconv<<<(D_IN * D_H + 255) / 256, 256, 0, stream>>>(W1, W1h, W1l, D_IN, D_H);
    k_wconv<<<(D_H * D_H + 255) / 256, 256, 0, stream>>>(W2, W2h, W2l, D_H, D_H);
    k_wconv<<<(D_H * D_IN + 255) / 256, 256, 0, stream>>>(L1w, L1h, L1l, D_H, D_IN);
    k_wconv<<<(D_IN * D_H + 255) / 256, 256, 0, stream>>>(L2w, L2h, L2l, D_IN, D_H);
    k_wconv<<<(D_H * D_OUT + 255) / 256, 256, 0, stream>>>(W3, W3h, W3l, D_H, D_OUT);

    // build CSR for adj (graph 1)
    hipMemsetAsync(tmp, 0, NNODES * 4, stream);
    k_hist<<<EB, 256, 0, stream>>>(adj + NEDGES, tmp, NEDGES);
    k_scan<<<1, 1024, 0, stream>>>(tmp, rp1, NNODES);
    k_dinv<<<NB, 256, 0, stream>>>(tmp, dinv1, NNODES);
    hipMemsetAsync(tmp, 0, NNODES * 4, stream);
    k_scatter<<<EB, 256, 0, stream>>>(adj, adj + NEDGES, rp1, tmp, col1, NEDGES);

    // build CSR for adj2 (graph 2)
    hipMemsetAsync(tmp, 0, NNODES * 4, stream);
    k_hist<<<EB, 256, 0, stream>>>(adj2 + NEDGES, tmp, NEDGES);
    k_scan<<<1, 1024, 0, stream>>>(tmp, rp2, NNODES);
    k_dinv<<<NB, 256, 0, stream>>>(tmp, dinv2, NNODES);
    hipMemsetAsync(tmp, 0, NNODES * 4, stream);
    k_scatter<<<EB, 256, 0, stream>>>(adj2, adj2 + NEDGES, rp2, tmp, col2, NEDGES);

    // conv1: h1 = relu((A1 x) W1 + b1)
    k_agg<128, false><<<AGB, 256, 0, stream>>>(x, rp1, col1, dinv1, nullptr, bufA, NNODES);
    k_gemm_mfma<true, true><<<dim3(MT, D_H / 64), 256, 0, stream>>>(bufA, W1h, W1l, b1, bufB, NNODES, D_IN, D_H);
    // conv2: h2 = relu((A2 h1) W2 + b2)
    k_agg<256, false><<<AGB, 256, 0, stream>>>(bufB, rp2, col2, dinv2, nullptr, bufA, NNODES);
    k_gemm_mfma<true, true><<<dim3(MT, D_H / 64), 256, 0, stream>>>(bufA, W2h, W2l, b2, bufB, NNODES, D_H, D_H);
    // h3 = relu(h2 L1w + L1b)
    k_gemm_mfma<true, true><<<dim3(MT, D_IN / 64), 256, 0, stream>>>(bufB, L1h, L1l, L1b, bufA, NNODES, D_H, D_IN);
    // h4 = relu(h3 L2w + L2b)
    k_gemm_mfma<true, true><<<dim3(MT, D_H / 64), 256, 0, stream>>>(bufA, L2h, L2l, L2b, bufB, NNODES, D_IN, D_H);
    // conv3: out = A2 (h4 W3) + b3
    k_gemm_mfma<false, false><<<dim3(MT, D_OUT / 64), 256, 0, stream>>>(bufB, W3h, W3l, nullptr, bufA, NNODES, D_H, D_OUT);
    k_agg<64, true><<<AGB, 256, 0, stream>>>(bufA, rp2, col2, dinv2, b3, out, NNODES);
    // optional softmax (mode != 1)
    k_softmax<<<AGB, 256, 0, stream>>>(out, mode, NNODES);
}

// Round 3
// 566.956 us; speedup vs baseline: 1.5852x; 1.4651x over previous
//
#include <hip/hip_runtime.h>
#include <hip/hip_bf16.h>
#include <cstdint>
#include <cstddef>

#define NNODES 50000
#define NEDGES 800000
#define D_IN   128
#define D_H    256
#define D_OUT  64
#define SCAN_BS 256
#define SCAN_NB ((NNODES + SCAN_BS - 1) / SCAN_BS)   // 196

typedef __attribute__((ext_vector_type(8))) short bf16x8;
typedef __attribute__((ext_vector_type(4))) float f32x4;

__device__ __forceinline__ unsigned short f2bf(float f) {
    unsigned u = __builtin_bit_cast(unsigned, f);
    unsigned r = (u + 0x7FFFu + ((u >> 16) & 1u)) >> 16;
    return (unsigned short)r;
}
__device__ __forceinline__ float bf2f(unsigned short h) {
    unsigned u = ((unsigned)h) << 16;
    return __builtin_bit_cast(float, u);
}

// ---------------- CSR build ----------------

__global__ void k_hist(const int* __restrict__ dst, int* __restrict__ cnt, int e) {
    int i = blockIdx.x * blockDim.x + threadIdx.x;
    if (i < e) atomicAdd(&cnt[dst[i]], 1);
}

__global__ __launch_bounds__(256) void k_scan_local(const int* __restrict__ cnt, int* __restrict__ rp,
                                                    int* __restrict__ bsum, int n) {
    __shared__ int s[SCAN_BS];
    int t = threadIdx.x;
    int i = blockIdx.x * SCAN_BS + t;
    int v = (i < n) ? cnt[i] : 0;
    int sum = v;
    s[t] = v;
    __syncthreads();
    #pragma unroll
    for (int off = 1; off < SCAN_BS; off <<= 1) {
        int u = (t >= off) ? s[t - off] : 0;
        __syncthreads();
        sum += u;
        s[t] = sum;
        __syncthreads();
    }
    if (i < n) rp[i] = sum - v;               // exclusive, pending block offset
    if (t == SCAN_BS - 1) bsum[blockIdx.x] = sum;
}

__global__ __launch_bounds__(256) void k_scan_top(int* __restrict__ bsum, int nb) {
    __shared__ int s[SCAN_BS];
    int t = threadIdx.x;
    int v = (t < nb) ? bsum[t] : 0;
    int sum = v;
    s[t] = v;
    __syncthreads();
    #pragma unroll
    for (int off = 1; off < SCAN_BS; off <<= 1) {
        int u = (t >= off) ? s[t - off] : 0;
        __syncthreads();
        sum += u;
        s[t] = sum;
        __syncthreads();
    }
    if (t < nb) bsum[t] = sum - v;            // exclusive
}

__global__ __launch_bounds__(256) void k_scan_add(int* __restrict__ rp, const int* __restrict__ bsum, int n) {
    int i = blockIdx.x * SCAN_BS + threadIdx.x;
    if (i < n) rp[i] += bsum[blockIdx.x];
    if (i == 0) rp[n] = NEDGES;               // degrees sum to E exactly
}

__global__ void k_dinv(const int* __restrict__ cnt, float* __restrict__ dinv, int n) {
    int i = blockIdx.x * blockDim.x + threadIdx.x;
    if (i < n) dinv[i] = rsqrtf((float)(cnt[i] + 1));  // +1 self loop
}

__global__ void k_scatter(const int* __restrict__ src, const int* __restrict__ dst,
                          const int* __restrict__ rp, int* __restrict__ cur,
                          int* __restrict__ col, int e) {
    int i = blockIdx.x * blockDim.x + threadIdx.x;
    if (i < e) {
        int d = dst[i];
        int p = rp[d] + atomicAdd(&cur[d], 1);
        col[p] = src[i];
    }
}

// ---------------- x prescale: g = x * dinv1[row]  (F=128) ----------------

__global__ __launch_bounds__(256) void k_prescale(const float* __restrict__ x, const float* __restrict__ dinv,
                                                  float* __restrict__ g, int total4) {
    int idx = blockIdx.x * blockDim.x + threadIdx.x;
    if (idx >= total4) return;
    int row = idx >> 5;                        // F/4 = 32 float4 per row
    float d = dinv[row];
    float4 v = ((const float4*)x)[idx];
    v.x *= d; v.y *= d; v.z *= d; v.w *= d;
    ((float4*)g)[idx] = v;
}

// ---------------- Aggregation over prescaled fp32 input ----------------
// out_pre[i] = dinv[i] * (sum_{j in N(i)} g[j] + g[i]),  g = dinv .* h
// OUTM: 0 -> hi/lo bf16 planes [i][2F]; 1 -> fp32 + bias (final output)

template<int F, int OUTM>
__global__ __launch_bounds__(256) void k_agg2(const float* __restrict__ g, const int* __restrict__ rp,
                                              const int* __restrict__ col, const float* __restrict__ dinv,
                                              const float* __restrict__ bias, void* __restrict__ outv, int n) {
    constexpr int VPT = F / 64;
    const int lane = threadIdx.x & 63;
    const int i = blockIdx.x * 4 + (threadIdx.x >> 6);
    if (i >= n) return;
    const float* gl = g + lane * VPT;
    float acc[VPT];
    #pragma unroll
    for (int c = 0; c < VPT; ++c) acc[c] = 0.f;

    int k = rp[i], end = rp[i + 1];

    if constexpr (VPT == 4) {
        {   // self loop
            float4 v = *(const float4*)(gl + (size_t)i * F);
            acc[0] += v.x; acc[1] += v.y; acc[2] += v.z; acc[3] += v.w;
        }
        for (; k + 4 <= end; k += 4) {
            int j0 = col[k], j1 = col[k + 1], j2 = col[k + 2], j3 = col[k + 3];
            float4 v0 = *(const float4*)(gl + (size_t)j0 * F);
            float4 v1 = *(const float4*)(gl + (size_t)j1 * F);
            float4 v2 = *(const float4*)(gl + (size_t)j2 * F);
            float4 v3 = *(const float4*)(gl + (size_t)j3 * F);
            acc[0] += v0.x + v1.x + v2.x + v3.x;
            acc[1] += v0.y + v1.y + v2.y + v3.y;
            acc[2] += v0.z + v1.z + v2.z + v3.z;
            acc[3] += v0.w + v1.w + v2.w + v3.w;
        }
        for (; k < end; ++k) {
            float4 v = *(const float4*)(gl + (size_t)col[k] * F);
            acc[0] += v.x; acc[1] += v.y; acc[2] += v.z; acc[3] += v.w;
        }
    } else if constexpr (VPT == 2) {
        {
            float2 v = *(const float2*)(gl + (size_t)i * F);
            acc[0] += v.x; acc[1] += v.y;
        }
        for (; k + 4 <= end; k += 4) {
            int j0 = col[k], j1 = col[k + 1], j2 = col[k + 2], j3 = col[k + 3];
            float2 v0 = *(const float2*)(gl + (size_t)j0 * F);
            float2 v1 = *(const float2*)(gl + (size_t)j1 * F);
            float2 v2 = *(const float2*)(gl + (size_t)j2 * F);
            float2 v3 = *(const float2*)(gl + (size_t)j3 * F);
            acc[0] += v0.x + v1.x + v2.x + v3.x;
            acc[1] += v0.y + v1.y + v2.y + v3.y;
        }
        for (; k < end; ++k) {
            float2 v = *(const float2*)(gl + (size_t)col[k] * F);
            acc[0] += v.x; acc[1] += v.y;
        }
    } else {
        acc[0] += gl[(size_t)i * F];
        for (; k + 4 <= end; k += 4) {
            int j0 = col[k], j1 = col[k + 1], j2 = col[k + 2], j3 = col[k + 3];
            float v0 = gl[(size_t)j0 * F];
            float v1 = gl[(size_t)j1 * F];
            float v2 = gl[(size_t)j2 * F];
            float v3 = gl[(size_t)j3 * F];
            acc[0] += v0 + v1 + v2 + v3;
        }
        for (; k < end; ++k) acc[0] += gl[(size_t)col[k] * F];
    }

    float di = dinv[i];
    if constexpr (OUTM == 0) {
        unsigned short* o = (unsigned short*)outv + (size_t)i * 2 * F + lane * VPT;
        #pragma unroll
        for (int c = 0; c < VPT; ++c) {
            float val = acc[c] * di;
            unsigned short h = f2bf(val);
            unsigned short l = f2bf(val - bf2f(h));
            o[c] = h;
            o[F + c] = l;
        }
    } else {
        float* o = (float*)outv + (size_t)i * F + lane * VPT;
        #pragma unroll
        for (int c = 0; c < VPT; ++c) o[c] = acc[c] * di + bias[lane * VPT + c];
    }
}

// ---------------- weight preconvert: W[K][N] fp32 -> Bt_hi/Bt_lo [N][K] bf16 ----------------

__global__ void k_wconv(const float* __restrict__ W, unsigned short* __restrict__ Th,
                        unsigned short* __restrict__ Tl, int K, int Nc) {
    int idx = blockIdx.x * blockDim.x + threadIdx.x;
    if (idx >= K * Nc) return;
    int k = idx / Nc, n = idx - k * Nc;
    float v = W[idx];
    unsigned short h = f2bf(v);
    unsigned short l = f2bf(v - bf2f(h));
    Th[(size_t)n * K + k] = h;
    Tl[(size_t)n * K + k] = l;
}

// ---------------- MFMA GEMM (bf16x3 split fp32 emulation), A in hi/lo planes ----------------
// A: [M][2K] shorts (hi | lo). C: OUTM=1 -> fp32 * dscale[row]; OUTM=2 -> hi/lo planes [M][2N].
// Tile 128x64, BK=64, 4 waves.

template<bool RELU, bool BIAS, int OUTM>
__global__ __launch_bounds__(256) void k_gemm_mfma(const unsigned short* __restrict__ Ahl,
        const unsigned short* __restrict__ Bth, const unsigned short* __restrict__ Btl,
        const float* __restrict__ bias, const float* __restrict__ dscale,
        void* __restrict__ Cv, int M, int K, int Nc) {
    constexpr int PAD = 66;  // 132B stride -> bank (33r+..)%32, conflict-free b128
    __shared__ unsigned short As_h[128][PAD];
    __shared__ unsigned short As_l[128][PAD];
    __shared__ unsigned short Bs_h[64][PAD];
    __shared__ unsigned short Bs_l[64][PAD];

    const int tid = threadIdx.x;
    const int lane = tid & 63;
    const int wv = tid >> 6;
    const int row0 = blockIdx.x * 128;
    const int col0 = blockIdx.y * 64;

    f32x4 acc[2][4];
    #pragma unroll
    for (int m = 0; m < 2; ++m)
        #pragma unroll
        for (int n = 0; n < 4; ++n) acc[m][n] = (f32x4)(0.f);

    // A staging: thread covers row srow, 32 k-values (hi + lo)
    const int srow = tid >> 1;
    const int skh = (tid & 1) * 32;
    int arow = row0 + srow;
    if (arow >= M) arow = M - 1;              // safe clamp; C store guarded
    const unsigned short* aph = Ahl + (size_t)arow * 2 * K + skh;
    const unsigned short* apl = aph + K;

    // B staging: thread covers col bn, 16 k-values
    const int bn = tid >> 2;
    const int bko = (tid & 3) * 16;
    const unsigned short* bph = Bth + (size_t)(col0 + bn) * K + bko;
    const unsigned short* bpl = Btl + (size_t)(col0 + bn) * K + bko;

    const int fr = lane & 15;
    const int fk = (lane >> 4) * 8;

    const int nk = K >> 6;
    for (int kt = 0; kt < nk; ++kt) {
        uint4 ah0 = *(const uint4*)(aph + kt * 64);
        uint4 ah1 = *(const uint4*)(aph + kt * 64 + 8);
        uint4 ah2 = *(const uint4*)(aph + kt * 64 + 16);
        uint4 ah3 = *(const uint4*)(aph + kt * 64 + 24);
        uint4 al0 = *(const uint4*)(apl + kt * 64);
        uint4 al1 = *(const uint4*)(apl + kt * 64 + 8);
        uint4 al2 = *(const uint4*)(apl + kt * 64 + 16);
        uint4 al3 = *(const uint4*)(apl + kt * 64 + 24);
        uint4 bh0 = *(const uint4*)(bph + kt * 64);
        uint4 bh1 = *(const uint4*)(bph + kt * 64 + 8);
        uint4 bl0 = *(const uint4*)(bpl + kt * 64);
        uint4 bl1 = *(const uint4*)(bpl + kt * 64 + 8);

        __syncthreads();  // previous tile's reads complete

        *(uint4*)&As_h[srow][skh] = ah0;
        *(uint4*)&As_h[srow][skh + 8] = ah1;
        *(uint4*)&As_h[srow][skh + 16] = ah2;
        *(uint4*)&As_h[srow][skh + 24] = ah3;
        *(uint4*)&As_l[srow][skh] = al0;
        *(uint4*)&As_l[srow][skh + 8] = al1;
        *(uint4*)&As_l[srow][skh + 16] = al2;
        *(uint4*)&As_l[srow][skh + 24] = al3;
        *(uint4*)&Bs_h[bn][bko] = bh0;
        *(uint4*)&Bs_h[bn][bko + 8] = bh1;
        *(uint4*)&Bs_l[bn][bko] = bl0;
        *(uint4*)&Bs_l[bn][bko + 8] = bl1;

        __syncthreads();

        #pragma unroll
        for (int ks = 0; ks < 2; ++ks) {
            const int ko = ks * 32 + fk;
            bf16x8 ah[2], al[2], bh[4], bl[4];
            #pragma unroll
            for (int m = 0; m < 2; ++m) {
                ah[m] = *(const bf16x8*)&As_h[wv * 32 + m * 16 + fr][ko];
                al[m] = *(const bf16x8*)&As_l[wv * 32 + m * 16 + fr][ko];
            }
            #pragma unroll
            for (int n = 0; n < 4; ++n) {
                bh[n] = *(const bf16x8*)&Bs_h[n * 16 + fr][ko];
                bl[n] = *(const bf16x8*)&Bs_l[n * 16 + fr][ko];
            }
            #pragma unroll
            for (int m = 0; m < 2; ++m)
                #pragma unroll
                for (int n = 0; n < 4; ++n) {
                    acc[m][n] = __builtin_amdgcn_mfma_f32_16x16x32_bf16(ah[m], bh[n], acc[m][n], 0, 0, 0);
                    acc[m][n] = __builtin_amdgcn_mfma_f32_16x16x32_bf16(ah[m], bl[n], acc[m][n], 0, 0, 0);
                    acc[m][n] = __builtin_amdgcn_mfma_f32_16x16x32_bf16(al[m], bh[n], acc[m][n], 0, 0, 0);
                }
        }
    }

    // epilogue: D col = lane&15, row = (lane>>4)*4 + j
    float bv[4];
    #pragma unroll
    for (int n = 0; n < 4; ++n) bv[n] = BIAS ? bias[col0 + n * 16 + fr] : 0.f;
    const int rbase = row0 + wv * 32 + (lane >> 4) * 4;
    #pragma unroll
    for (int m = 0; m < 2; ++m) {
        #pragma unroll
        for (int j = 0; j < 4; ++j) {
            const int r = rbase + m * 16 + j;
            if (r >= M) continue;
            float ds = 1.f;
            if constexpr (OUTM == 1) ds = dscale[r];
            #pragma unroll
            for (int n = 0; n < 4; ++n) {
                const int c = col0 + n * 16 + fr;
                float o = acc[m][n][j] + bv[n];
                if constexpr (RELU) o = fmaxf(o, 0.f);
                if constexpr (OUTM == 1) {
                    ((float*)Cv)[(size_t)r * Nc + c] = o * ds;
                } else {
                    unsigned short h = f2bf(o);
                    unsigned short l = f2bf(o - bf2f(h));
                    unsigned short* C2 = (unsigned short*)Cv + (size_t)r * 2 * Nc + c;
                    C2[0] = h;
                    C2[Nc] = l;
                }
            }
        }
    }
}

// ---------------- conditional softmax over 64 classes ----------------

__global__ __launch_bounds__(256) void k_softmax(float* __restrict__ out, const int* __restrict__ mode, int n) {
    if (*mode == 1) return;
    int wave = threadIdx.x >> 6;
    int lane = threadIdx.x & 63;
    int i = blockIdx.x * 4 + wave;
    if (i >= n) return;
    float v = out[(size_t)i * 64 + lane];
    float m = v;
    #pragma unroll
    for (int off = 32; off > 0; off >>= 1) m = fmaxf(m, __shfl_xor(m, off));
    float e = __expf(v - m);
    float s = e;
    #pragma unroll
    for (int off = 32; off > 0; off >>= 1) s += __shfl_xor(s, off);
    out[(size_t)i * 64 + lane] = e / s;
}

// ---------------- launch ----------------

extern "C" void kernel_launch(void* const* d_in, const int* in_sizes, int n_in,
                              void* d_out, int out_size, void* d_ws, size_t ws_size,
                              hipStream_t stream) {
    const float* x   = (const float*)d_in[0];
    const float* W1  = (const float*)d_in[1];
    const float* b1  = (const float*)d_in[2];
    const float* W2  = (const float*)d_in[3];
    const float* b2  = (const float*)d_in[4];
    const float* L1w = (const float*)d_in[5];
    const float* L1b = (const float*)d_in[6];
    const float* L2w = (const float*)d_in[7];
    const float* L2b = (const float*)d_in[8];
    const float* W3  = (const float*)d_in[9];
    const float* b3  = (const float*)d_in[10];
    const int* adj   = (const int*)d_in[11];
    const int* adj2  = (const int*)d_in[12];
    const int* mode  = (const int*)d_in[13];
    float* out = (float*)d_out;

    char* ws = (char*)d_ws;
    auto alloc = [&](size_t bytes) {
        char* p = ws;
        ws += (bytes + 255) & ~(size_t)255;
        return p;
    };
    char*  bufA  = alloc((size_t)NNODES * 256 * 4);   // 51.2 MB raw (f32[256] or hl[2*256] shorts)
    char*  bufB  = alloc((size_t)NNODES * 256 * 4);
    int*   rp1   = (int*)alloc((NNODES + 1) * 4);
    int*   col1  = (int*)alloc((size_t)NEDGES * 4);
    int*   rp2   = (int*)alloc((NNODES + 1) * 4);
    int*   col2  = (int*)alloc((size_t)NEDGES * 4);
    float* dinv1 = (float*)alloc(NNODES * 4);
    float* dinv2 = (float*)alloc(NNODES * 4);
    int*   tmp   = (int*)alloc(NNODES * 4);
    int*   bsum  = (int*)alloc(SCAN_NB * 4);
    unsigned short* W1h = (unsigned short*)alloc(D_IN * D_H * 2);
    unsigned short* W1l = (unsigned short*)alloc(D_IN * D_H * 2);
    unsigned short* W2h = (unsigned short*)alloc(D_H * D_H * 2);
    unsigned short* W2l = (unsigned short*)alloc(D_H * D_H * 2);
    unsigned short* L1h = (unsigned short*)alloc(D_H * D_IN * 2);
    unsigned short* L1l = (unsigned short*)alloc(D_H * D_IN * 2);
    unsigned short* L2h = (unsigned short*)alloc(D_IN * D_H * 2);
    unsigned short* L2l = (unsigned short*)alloc(D_IN * D_H * 2);
    unsigned short* W3h = (unsigned short*)alloc(D_H * D_OUT * 2);
    unsigned short* W3l = (unsigned short*)alloc(D_H * D_OUT * 2);

    const int EB = (NEDGES + 255) / 256;
    const int NB = (NNODES + 255) / 256;
    const int AGB = (NNODES + 3) / 4;
    const int MT = (NNODES + 127) / 128;

    // weight conversion (tiny)
    k_wconv<<<(D_IN * D_H + 255) / 256, 256, 0, stream>>>(W1, W1h, W1l, D_IN, D_H);
    k_wconv<<<(D_H * D_H + 255) / 256, 256, 0, stream>>>(W2, W2h, W2l, D_H, D_H);
    k_wconv<<<(D_H * D_IN + 255) / 256, 256, 0, stream>>>(L1w, L1h, L1l, D_H, D_IN);
    k_wconv<<<(D_IN * D_H + 255) / 256, 256, 0, stream>>>(L2w, L2h, L2l, D_IN, D_H);
    k_wconv<<<(D_H * D_OUT + 255) / 256, 256, 0, stream>>>(W3, W3h, W3l, D_H, D_OUT);

    // CSR graph 1
    hipMemsetAsync(tmp, 0, NNODES * 4, stream);
    k_hist<<<EB, 256, 0, stream>>>(adj + NEDGES, tmp, NEDGES);
    k_scan_local<<<SCAN_NB, 256, 0, stream>>>(tmp, rp1, bsum, NNODES);
    k_scan_top<<<1, 256, 0, stream>>>(bsum, SCAN_NB);
    k_scan_add<<<SCAN_NB, 256, 0, stream>>>(rp1, bsum, NNODES);
    k_dinv<<<NB, 256, 0, stream>>>(tmp, dinv1, NNODES);
    hipMemsetAsync(tmp, 0, NNODES * 4, stream);
    k_scatter<<<EB, 256, 0, stream>>>(adj, adj + NEDGES, rp1, tmp, col1, NEDGES);

    // CSR graph 2
    hipMemsetAsync(tmp, 0, NNODES * 4, stream);
    k_hist<<<EB, 256, 0, stream>>>(adj2 + NEDGES, tmp, NEDGES);
    k_scan_local<<<SCAN_NB, 256, 0, stream>>>(tmp, rp2, bsum, NNODES);
    k_scan_top<<<1, 256, 0, stream>>>(bsum, SCAN_NB);
    k_scan_add<<<SCAN_NB, 256, 0, stream>>>(rp2, bsum, NNODES);
    k_dinv<<<NB, 256, 0, stream>>>(tmp, dinv2, NNODES);
    hipMemsetAsync(tmp, 0, NNODES * 4, stream);
    k_scatter<<<EB, 256, 0, stream>>>(adj2, adj2 + NEDGES, rp2, tmp, col2, NEDGES);

    // g = x .* dinv1  (fp32)
    k_prescale<<<(NNODES * D_IN / 4 + 255) / 256, 256, 0, stream>>>(x, dinv1, (float*)bufA, NNODES * D_IN / 4);

    // conv1 agg: bufA(f32,128) -> bufB (hl,128)
    k_agg2<128, 0><<<AGB, 256, 0, stream>>>((const float*)bufA, rp1, col1, dinv1, nullptr, bufB, NNODES);
    // conv1 gemm: relu((. )W1+b1) * dinv2 -> bufA (f32,256)
    k_gemm_mfma<true, true, 1><<<dim3(MT, D_H / 64), 256, 0, stream>>>(
        (const unsigned short*)bufB, W1h, W1l, b1, dinv2, bufA, NNODES, D_IN, D_H);
    // conv2 agg: bufA(f32,256) -> bufB (hl,256)
    k_agg2<256, 0><<<AGB, 256, 0, stream>>>((const float*)bufA, rp2, col2, dinv2, nullptr, bufB, NNODES);
    // conv2 gemm: relu((. )W2+b2) -> bufA (hl,256)
    k_gemm_mfma<true, true, 2><<<dim3(MT, D_H / 64), 256, 0, stream>>>(
        (const unsigned short*)bufB, W2h, W2l, b2, nullptr, bufA, NNODES, D_H, D_H);
    // L1: relu((. )L1w+b) -> bufB (hl,128)
    k_gemm_mfma<true, true, 2><<<dim3(MT, D_IN / 64), 256, 0, stream>>>(
        (const unsigned short*)bufA, L1h, L1l, L1b, nullptr, bufB, NNODES, D_H, D_IN);
    // L2: relu((. )L2w+b) -> bufA (hl,256)
    k_gemm_mfma<true, true, 2><<<dim3(MT, D_H / 64), 256, 0, stream>>>(
        (const unsigned short*)bufB, L2h, L2l, L2b, nullptr, bufA, NNODES, D_IN, D_H);
    // conv3 gemm: ((. )W3) * dinv2 -> bufB (f32,64)
    k_gemm_mfma<false, false, 1><<<dim3(MT, D_OUT / 64), 256, 0, stream>>>(
        (const unsigned short*)bufA, W3h, W3l, nullptr, dinv2, bufB, NNODES, D_H, D_OUT);
    // conv3 agg: bufB(f32,64) -> out (f32 + b3)
    k_agg2<64, 1><<<AGB, 256, 0, stream>>>((const float*)bufB, rp2, col2, dinv2, b3, out, NNODES);
    // optional softmax (mode != 1)
    k_softmax<<<AGB, 256, 0, stream>>>(out, mode, NNODES);
}

// Round 4
// 486.272 us; speedup vs baseline: 1.8482x; 1.1659x over previous
//
#include <hip/hip_runtime.h>
#include <hip/hip_bf16.h>
#include <cstdint>
#include <cstddef>

#define NNODES 50000
#define NEDGES 800000
#define D_IN   128
#define D_H    256
#define D_OUT  64
#define SCAN_BS 256
#define SCAN_NB ((NNODES + SCAN_BS - 1) / SCAN_BS)   // 196

typedef __attribute__((ext_vector_type(8))) short bf16x8;
typedef __attribute__((ext_vector_type(4))) float f32x4;

__device__ __forceinline__ unsigned short f2bf(float f) {
    unsigned u = __builtin_bit_cast(unsigned, f);
    unsigned r = (u + 0x7FFFu + ((u >> 16) & 1u)) >> 16;
    return (unsigned short)r;
}
__device__ __forceinline__ float bf2f(unsigned short h) {
    unsigned u = ((unsigned)h) << 16;
    return __builtin_bit_cast(float, u);
}

// ---------------- CSR build (both graphs fused per stage) ----------------

__global__ void k_hist2(const int* __restrict__ dstA, const int* __restrict__ dstB,
                        int* __restrict__ cntA, int* __restrict__ cntB, int e) {
    int i = blockIdx.x * blockDim.x + threadIdx.x;
    if (i < e) atomicAdd(&cntA[dstA[i]], 1);
    else if (i < 2 * e) atomicAdd(&cntB[dstB[i - e]], 1);
}

__global__ __launch_bounds__(256) void k_scan_local2(const int* __restrict__ cnt1, const int* __restrict__ cnt2,
                                                     int* __restrict__ rp1, int* __restrict__ rp2,
                                                     int* __restrict__ bsum, int n) {
    __shared__ int s[SCAN_BS];
    const int g = blockIdx.x / SCAN_NB;
    const int blk = blockIdx.x - g * SCAN_NB;
    const int* cnt = g ? cnt2 : cnt1;
    int* rp = g ? rp2 : rp1;
    int t = threadIdx.x;
    int i = blk * SCAN_BS + t;
    int v = (i < n) ? cnt[i] : 0;
    int sum = v;
    s[t] = v;
    __syncthreads();
    #pragma unroll
    for (int off = 1; off < SCAN_BS; off <<= 1) {
        int u = (t >= off) ? s[t - off] : 0;
        __syncthreads();
        sum += u;
        s[t] = sum;
        __syncthreads();
    }
    if (i < n) rp[i] = sum - v;
    if (t == SCAN_BS - 1) bsum[blockIdx.x] = sum;   // [g*SCAN_NB + blk]
}

__global__ __launch_bounds__(256) void k_scan_top2(int* __restrict__ bsum) {
    __shared__ int s[SCAN_BS];
    int* b = bsum + blockIdx.x * SCAN_NB;
    int t = threadIdx.x;
    int v = (t < SCAN_NB) ? b[t] : 0;
    int sum = v;
    s[t] = v;
    __syncthreads();
    #pragma unroll
    for (int off = 1; off < SCAN_BS; off <<= 1) {
        int u = (t >= off) ? s[t - off] : 0;
        __syncthreads();
        sum += u;
        s[t] = sum;
        __syncthreads();
    }
    if (t < SCAN_NB) b[t] = sum - v;
}

__global__ __launch_bounds__(256) void k_scan_add2(int* __restrict__ rp1, int* __restrict__ rp2,
                                                   const int* __restrict__ bsum, int n) {
    const int g = blockIdx.x / SCAN_NB;
    const int blk = blockIdx.x - g * SCAN_NB;
    int* rp = g ? rp2 : rp1;
    int i = blk * SCAN_BS + threadIdx.x;
    if (i < n) rp[i] += bsum[blockIdx.x];
    if (i == 0) rp[n] = NEDGES;
}

__global__ void k_dinv2x(const int* __restrict__ cnt1, const int* __restrict__ cnt2,
                         float* __restrict__ dinv1, float* __restrict__ dinv2, int n) {
    int i = blockIdx.x * blockDim.x + threadIdx.x;
    if (i < n) dinv1[i] = rsqrtf((float)(cnt1[i] + 1));
    else if (i < 2 * n) dinv2[i - n] = rsqrtf((float)(cnt2[i - n] + 1));
}

__global__ void k_scatter2(const int* __restrict__ adjA, const int* __restrict__ adjB,
                           const int* __restrict__ rp1, const int* __restrict__ rp2,
                           int* __restrict__ cur1, int* __restrict__ cur2,
                           int* __restrict__ col1, int* __restrict__ col2, int e) {
    int i = blockIdx.x * blockDim.x + threadIdx.x;
    if (i < e) {
        int d = adjA[e + i];
        int p = rp1[d] + atomicAdd(&cur1[d], 1);
        col1[p] = adjA[i];
    } else if (i < 2 * e) {
        int j = i - e;
        int d = adjB[e + j];
        int p = rp2[d] + atomicAdd(&cur2[d], 1);
        col2[p] = adjB[j];
    }
}

// ---------------- quantize: fp32 rows -> int16 rows + per-row scale ----------------
// One wave per row. PRESCALE: multiply row by dscale[row] first (used for x * dinv1).

template<int F, bool PRESCALE>
__global__ __launch_bounds__(256) void k_quant(const float* __restrict__ in, const float* __restrict__ dscale,
                                               short* __restrict__ q, float* __restrict__ qs, int n) {
    constexpr int VPT = F / 64;
    const int lane = threadIdx.x & 63;
    const int i = blockIdx.x * 4 + (threadIdx.x >> 6);
    if (i >= n) return;
    float v[VPT];
    const float* p = in + (size_t)i * F + lane * VPT;
    if constexpr (VPT == 4) { float4 t = *(const float4*)p; v[0] = t.x; v[1] = t.y; v[2] = t.z; v[3] = t.w; }
    else if constexpr (VPT == 2) { float2 t = *(const float2*)p; v[0] = t.x; v[1] = t.y; }
    else v[0] = *p;
    if constexpr (PRESCALE) {
        float d = dscale[i];
        #pragma unroll
        for (int c = 0; c < VPT; ++c) v[c] *= d;
    }
    float m = 0.f;
    #pragma unroll
    for (int c = 0; c < VPT; ++c) m = fmaxf(m, fabsf(v[c]));
    #pragma unroll
    for (int off = 32; off > 0; off >>= 1) m = fmaxf(m, __shfl_xor(m, off));
    float inv = (m > 0.f) ? 32767.0f / m : 0.f;
    short* qp = q + (size_t)i * F + lane * VPT;
    if constexpr (VPT == 4) {
        short4 o;
        o.x = (short)__float2int_rn(v[0] * inv);
        o.y = (short)__float2int_rn(v[1] * inv);
        o.z = (short)__float2int_rn(v[2] * inv);
        o.w = (short)__float2int_rn(v[3] * inv);
        *(short4*)qp = o;
    } else if constexpr (VPT == 2) {
        short2 o;
        o.x = (short)__float2int_rn(v[0] * inv);
        o.y = (short)__float2int_rn(v[1] * inv);
        *(short2*)qp = o;
    } else {
        *qp = (short)__float2int_rn(v[0] * inv);
    }
    if (lane == 0) qs[i] = m * (1.0f / 32767.0f);
}

// ---------------- Aggregation over int16-quantized prescaled input ----------------
// out[i] = dinv[i] * (sum_{j in N(i)} s_j*q[j] + s_i*q[i])   (+bias for OUTM=1)
// OUTM: 0 -> hi/lo bf16 planes [i][2F]; 1 -> fp32 + bias (final output)

template<int F, int OUTM>
__global__ __launch_bounds__(256) void k_agg3(const short* __restrict__ q, const float* __restrict__ qs,
                                              const int* __restrict__ rp, const int* __restrict__ col,
                                              const float* __restrict__ dinv, const float* __restrict__ bias,
                                              void* __restrict__ outv, int n) {
    constexpr int VPT = F / 64;
    const int lane = threadIdx.x & 63;
    const int i = blockIdx.x * 4 + (threadIdx.x >> 6);
    if (i >= n) return;
    const short* ql = q + lane * VPT;
    float acc[VPT];
    #pragma unroll
    for (int c = 0; c < VPT; ++c) acc[c] = 0.f;

    int k = rp[i], end = rp[i + 1];

    auto body1 = [&](int j) {
        float s = qs[j];
        const short* pj = ql + (size_t)j * F;
        if constexpr (VPT == 4) {
            short4 v = *(const short4*)pj;
            acc[0] += s * (float)v.x; acc[1] += s * (float)v.y;
            acc[2] += s * (float)v.z; acc[3] += s * (float)v.w;
        } else if constexpr (VPT == 2) {
            short2 v = *(const short2*)pj;
            acc[0] += s * (float)v.x; acc[1] += s * (float)v.y;
        } else {
            acc[0] += s * (float)(*pj);
        }
    };

    body1(i);  // self loop
    for (; k + 4 <= end; k += 4) {
        int j0 = col[k], j1 = col[k + 1], j2 = col[k + 2], j3 = col[k + 3];
        float s0 = qs[j0], s1 = qs[j1], s2 = qs[j2], s3 = qs[j3];
        if constexpr (VPT == 4) {
            short4 v0 = *(const short4*)(ql + (size_t)j0 * F);
            short4 v1 = *(const short4*)(ql + (size_t)j1 * F);
            short4 v2 = *(const short4*)(ql + (size_t)j2 * F);
            short4 v3 = *(const short4*)(ql + (size_t)j3 * F);
            acc[0] += s0 * (float)v0.x + s1 * (float)v1.x + s2 * (float)v2.x + s3 * (float)v3.x;
            acc[1] += s0 * (float)v0.y + s1 * (float)v1.y + s2 * (float)v2.y + s3 * (float)v3.y;
            acc[2] += s0 * (float)v0.z + s1 * (float)v1.z + s2 * (float)v2.z + s3 * (float)v3.z;
            acc[3] += s0 * (float)v0.w + s1 * (float)v1.w + s2 * (float)v2.w + s3 * (float)v3.w;
        } else if constexpr (VPT == 2) {
            short2 v0 = *(const short2*)(ql + (size_t)j0 * F);
            short2 v1 = *(const short2*)(ql + (size_t)j1 * F);
            short2 v2 = *(const short2*)(ql + (size_t)j2 * F);
            short2 v3 = *(const short2*)(ql + (size_t)j3 * F);
            acc[0] += s0 * (float)v0.x + s1 * (float)v1.x + s2 * (float)v2.x + s3 * (float)v3.x;
            acc[1] += s0 * (float)v0.y + s1 * (float)v1.y + s2 * (float)v2.y + s3 * (float)v3.y;
        } else {
            float v0 = (float)ql[(size_t)j0 * F];
            float v1 = (float)ql[(size_t)j1 * F];
            float v2 = (float)ql[(size_t)j2 * F];
            float v3 = (float)ql[(size_t)j3 * F];
            acc[0] += s0 * v0 + s1 * v1 + s2 * v2 + s3 * v3;
        }
    }
    for (; k < end; ++k) body1(col[k]);

    float di = dinv[i];
    if constexpr (OUTM == 0) {
        unsigned short* o = (unsigned short*)outv + (size_t)i * 2 * F + lane * VPT;
        #pragma unroll
        for (int c = 0; c < VPT; ++c) {
            float val = acc[c] * di;
            unsigned short h = f2bf(val);
            unsigned short l = f2bf(val - bf2f(h));
            o[c] = h;
            o[F + c] = l;
        }
    } else {
        float* o = (float*)outv + (size_t)i * F + lane * VPT;
        #pragma unroll
        for (int c = 0; c < VPT; ++c) o[c] = acc[c] * di + bias[lane * VPT + c];
    }
}

// ---------------- fused weight preconvert: all 5 weights -> hi/lo [N][K] bf16 ----------------

__device__ __forceinline__ void wconv1(const float* __restrict__ W, unsigned short* __restrict__ Th,
                                       unsigned short* __restrict__ Tl, int idx, int K, int Nc) {
    int k = idx / Nc, n = idx - k * Nc;
    float v = W[idx];
    unsigned short h = f2bf(v);
    unsigned short l = f2bf(v - bf2f(h));
    Th[(size_t)n * K + k] = h;
    Tl[(size_t)n * K + k] = l;
}

__global__ void k_wconv_all(const float* W1, const float* W2, const float* L1w, const float* L2w, const float* W3,
                            unsigned short* W1h, unsigned short* W1l, unsigned short* W2h, unsigned short* W2l,
                            unsigned short* L1h, unsigned short* L1l, unsigned short* L2h, unsigned short* L2l,
                            unsigned short* W3h, unsigned short* W3l) {
    int idx = blockIdx.x * blockDim.x + threadIdx.x;
    if (idx < 32768)        wconv1(W1, W1h, W1l, idx, D_IN, D_H);
    else if (idx < 98304)   wconv1(W2, W2h, W2l, idx - 32768, D_H, D_H);
    else if (idx < 131072)  wconv1(L1w, L1h, L1l, idx - 98304, D_H, D_IN);
    else if (idx < 163840)  wconv1(L2w, L2h, L2l, idx - 131072, D_IN, D_H);
    else if (idx < 180224)  wconv1(W3, W3h, W3l, idx - 163840, D_H, D_OUT);
}

// ---------------- MFMA GEMM (bf16x3 split fp32 emulation), A in hi/lo planes ----------------
// A: [M][2K] shorts (hi | lo). C: OUTM=1 -> fp32 * dscale[row]; OUTM=2 -> hi/lo planes [M][2N].

template<bool RELU, bool BIAS, int OUTM>
__global__ __launch_bounds__(256) void k_gemm_mfma(const unsigned short* __restrict__ Ahl,
        const unsigned short* __restrict__ Bth, const unsigned short* __restrict__ Btl,
        const float* __restrict__ bias, const float* __restrict__ dscale,
        void* __restrict__ Cv, int M, int K, int Nc) {
    constexpr int PAD = 66;
    __shared__ unsigned short As_h[128][PAD];
    __shared__ unsigned short As_l[128][PAD];
    __shared__ unsigned short Bs_h[64][PAD];
    __shared__ unsigned short Bs_l[64][PAD];

    const int tid = threadIdx.x;
    const int lane = tid & 63;
    const int wv = tid >> 6;
    const int row0 = blockIdx.x * 128;
    const int col0 = blockIdx.y * 64;

    f32x4 acc[2][4];
    #pragma unroll
    for (int m = 0; m < 2; ++m)
        #pragma unroll
        for (int n = 0; n < 4; ++n) acc[m][n] = (f32x4)(0.f);

    const int srow = tid >> 1;
    const int skh = (tid & 1) * 32;
    int arow = row0 + srow;
    if (arow >= M) arow = M - 1;
    const unsigned short* aph = Ahl + (size_t)arow * 2 * K + skh;
    const unsigned short* apl = aph + K;

    const int bn = tid >> 2;
    const int bko = (tid & 3) * 16;
    const unsigned short* bph = Bth + (size_t)(col0 + bn) * K + bko;
    const unsigned short* bpl = Btl + (size_t)(col0 + bn) * K + bko;

    const int fr = lane & 15;
    const int fk = (lane >> 4) * 8;

    const int nk = K >> 6;
    for (int kt = 0; kt < nk; ++kt) {
        uint4 ah0 = *(const uint4*)(aph + kt * 64);
        uint4 ah1 = *(const uint4*)(aph + kt * 64 + 8);
        uint4 ah2 = *(const uint4*)(aph + kt * 64 + 16);
        uint4 ah3 = *(const uint4*)(aph + kt * 64 + 24);
        uint4 al0 = *(const uint4*)(apl + kt * 64);
        uint4 al1 = *(const uint4*)(apl + kt * 64 + 8);
        uint4 al2 = *(const uint4*)(apl + kt * 64 + 16);
        uint4 al3 = *(const uint4*)(apl + kt * 64 + 24);
        uint4 bh0 = *(const uint4*)(bph + kt * 64);
        uint4 bh1 = *(const uint4*)(bph + kt * 64 + 8);
        uint4 bl0 = *(const uint4*)(bpl + kt * 64);
        uint4 bl1 = *(const uint4*)(bpl + kt * 64 + 8);

        __syncthreads();

        *(uint4*)&As_h[srow][skh] = ah0;
        *(uint4*)&As_h[srow][skh + 8] = ah1;
        *(uint4*)&As_h[srow][skh + 16] = ah2;
        *(uint4*)&As_h[srow][skh + 24] = ah3;
        *(uint4*)&As_l[srow][skh] = al0;
        *(uint4*)&As_l[srow][skh + 8] = al1;
        *(uint4*)&As_l[srow][skh + 16] = al2;
        *(uint4*)&As_l[srow][skh + 24] = al3;
        *(uint4*)&Bs_h[bn][bko] = bh0;
        *(uint4*)&Bs_h[bn][bko + 8] = bh1;
        *(uint4*)&Bs_l[bn][bko] = bl0;
        *(uint4*)&Bs_l[bn][bko + 8] = bl1;

        __syncthreads();

        #pragma unroll
        for (int ks = 0; ks < 2; ++ks) {
            const int ko = ks * 32 + fk;
            bf16x8 ah[2], al[2], bh[4], bl[4];
            #pragma unroll
            for (int m = 0; m < 2; ++m) {
                ah[m] = *(const bf16x8*)&As_h[wv * 32 + m * 16 + fr][ko];
                al[m] = *(const bf16x8*)&As_l[wv * 32 + m * 16 + fr][ko];
            }
            #pragma unroll
            for (int n = 0; n < 4; ++n) {
                bh[n] = *(const bf16x8*)&Bs_h[n * 16 + fr][ko];
                bl[n] = *(const bf16x8*)&Bs_l[n * 16 + fr][ko];
            }
            #pragma unroll
            for (int m = 0; m < 2; ++m)
                #pragma unroll
                for (int n = 0; n < 4; ++n) {
                    acc[m][n] = __builtin_amdgcn_mfma_f32_16x16x32_bf16(ah[m], bh[n], acc[m][n], 0, 0, 0);
                    acc[m][n] = __builtin_amdgcn_mfma_f32_16x16x32_bf16(ah[m], bl[n], acc[m][n], 0, 0, 0);
                    acc[m][n] = __builtin_amdgcn_mfma_f32_16x16x32_bf16(al[m], bh[n], acc[m][n], 0, 0, 0);
                }
        }
    }

    float bv[4];
    #pragma unroll
    for (int n = 0; n < 4; ++n) bv[n] = BIAS ? bias[col0 + n * 16 + fr] : 0.f;
    const int rbase = row0 + wv * 32 + (lane >> 4) * 4;
    #pragma unroll
    for (int m = 0; m < 2; ++m) {
        #pragma unroll
        for (int j = 0; j < 4; ++j) {
            const int r = rbase + m * 16 + j;
            if (r >= M) continue;
            float ds = 1.f;
            if constexpr (OUTM == 1) ds = dscale[r];
            #pragma unroll
            for (int n = 0; n < 4; ++n) {
                const int c = col0 + n * 16 + fr;
                float o = acc[m][n][j] + bv[n];
                if constexpr (RELU) o = fmaxf(o, 0.f);
                if constexpr (OUTM == 1) {
                    ((float*)Cv)[(size_t)r * Nc + c] = o * ds;
                } else {
                    unsigned short h = f2bf(o);
                    unsigned short l = f2bf(o - bf2f(h));
                    unsigned short* C2 = (unsigned short*)Cv + (size_t)r * 2 * Nc + c;
                    C2[0] = h;
                    C2[Nc] = l;
                }
            }
        }
    }
}

// ---------------- conditional softmax over 64 classes ----------------

__global__ __launch_bounds__(256) void k_softmax(float* __restrict__ out, const int* __restrict__ mode, int n) {
    if (*mode == 1) return;
    int lane = threadIdx.x & 63;
    int i = blockIdx.x * 4 + (threadIdx.x >> 6);
    if (i >= n) return;
    float v = out[(size_t)i * 64 + lane];
    float m = v;
    #pragma unroll
    for (int off = 32; off > 0; off >>= 1) m = fmaxf(m, __shfl_xor(m, off));
    float e = __expf(v - m);
    float s = e;
    #pragma unroll
    for (int off = 32; off > 0; off >>= 1) s += __shfl_xor(s, off);
    out[(size_t)i * 64 + lane] = e / s;
}

// ---------------- launch ----------------

extern "C" void kernel_launch(void* const* d_in, const int* in_sizes, int n_in,
                              void* d_out, int out_size, void* d_ws, size_t ws_size,
                              hipStream_t stream) {
    const float* x   = (const float*)d_in[0];
    const float* W1  = (const float*)d_in[1];
    const float* b1  = (const float*)d_in[2];
    const float* W2  = (const float*)d_in[3];
    const float* b2  = (const float*)d_in[4];
    const float* L1w = (const float*)d_in[5];
    const float* L1b = (const float*)d_in[6];
    const float* L2w = (const float*)d_in[7];
    const float* L2b = (const float*)d_in[8];
    const float* W3  = (const float*)d_in[9];
    const float* b3  = (const float*)d_in[10];
    const int* adj   = (const int*)d_in[11];
    const int* adj2  = (const int*)d_in[12];
    const int* mode  = (const int*)d_in[13];
    float* out = (float*)d_out;

    char* ws = (char*)d_ws;
    auto alloc = [&](size_t bytes) {
        char* p = ws;
        ws += (bytes + 255) & ~(size_t)255;
        return p;
    };
    char*  bufA  = alloc((size_t)NNODES * 256 * 4);   // 51.2 MB
    char*  bufB  = alloc((size_t)NNODES * 256 * 4);   // 51.2 MB
    int*   rp1   = (int*)alloc((NNODES + 1) * 4);
    int*   col1  = (int*)alloc((size_t)NEDGES * 4);
    int*   rp2   = (int*)alloc((NNODES + 1) * 4);
    int*   col2  = (int*)alloc((size_t)NEDGES * 4);
    float* dinv1 = (float*)alloc(NNODES * 4);
    float* dinv2 = (float*)alloc(NNODES * 4);
    int*   cnts  = (int*)alloc((size_t)4 * NNODES * 4);  // cnt1|cnt2|cur1|cur2 (one memset)
    int*   cnt1 = cnts, *cnt2 = cnts + NNODES, *cur1 = cnts + 2 * NNODES, *cur2 = cnts + 3 * NNODES;
    int*   bsum  = (int*)alloc(2 * SCAN_NB * 4);
    float* qs    = (float*)alloc(NNODES * 4);
    unsigned short* W1h = (unsigned short*)alloc(D_IN * D_H * 2);
    unsigned short* W1l = (unsigned short*)alloc(D_IN * D_H * 2);
    unsigned short* W2h = (unsigned short*)alloc(D_H * D_H * 2);
    unsigned short* W2l = (unsigned short*)alloc(D_H * D_H * 2);
    unsigned short* L1h = (unsigned short*)alloc(D_H * D_IN * 2);
    unsigned short* L1l = (unsigned short*)alloc(D_H * D_IN * 2);
    unsigned short* L2h = (unsigned short*)alloc(D_IN * D_H * 2);
    unsigned short* L2l = (unsigned short*)alloc(D_IN * D_H * 2);
    unsigned short* W3h = (unsigned short*)alloc(D_H * D_OUT * 2);
    unsigned short* W3l = (unsigned short*)alloc(D_H * D_OUT * 2);

    const int E2B = (2 * NEDGES + 255) / 256;
    const int AGB = (NNODES + 3) / 4;
    const int MT = (NNODES + 127) / 128;

    // weights -> bf16 hi/lo transposed (one kernel)
    k_wconv_all<<<(180224 + 255) / 256, 256, 0, stream>>>(W1, W2, L1w, L2w, W3,
        W1h, W1l, W2h, W2l, L1h, L1l, L2h, L2l, W3h, W3l);

    // CSR build, both graphs fused
    hipMemsetAsync(cnts, 0, (size_t)4 * NNODES * 4, stream);
    k_hist2<<<E2B, 256, 0, stream>>>(adj + NEDGES, adj2 + NEDGES, cnt1, cnt2, NEDGES);
    k_scan_local2<<<2 * SCAN_NB, 256, 0, stream>>>(cnt1, cnt2, rp1, rp2, bsum, NNODES);
    k_scan_top2<<<2, 256, 0, stream>>>(bsum);
    k_scan_add2<<<2 * SCAN_NB, 256, 0, stream>>>(rp1, rp2, bsum, NNODES);
    k_dinv2x<<<(2 * NNODES + 255) / 256, 256, 0, stream>>>(cnt1, cnt2, dinv1, dinv2, NNODES);
    k_scatter2<<<E2B, 256, 0, stream>>>(adj, adj2, rp1, rp2, cur1, cur2, col1, col2, NEDGES);

    // q(x .* dinv1) -> bufA (int16[50000][128]) + qs
    k_quant<128, true><<<AGB, 256, 0, stream>>>(x, dinv1, (short*)bufA, qs, NNODES);
    // conv1 agg: bufA(q128) -> bufB (hl,128)
    k_agg3<128, 0><<<AGB, 256, 0, stream>>>((const short*)bufA, qs, rp1, col1, dinv1, nullptr, bufB, NNODES);
    // conv1 gemm: relu((.)W1+b1) * dinv2 -> bufA (f32,256)
    k_gemm_mfma<true, true, 1><<<dim3(MT, D_H / 64), 256, 0, stream>>>(
        (const unsigned short*)bufB, W1h, W1l, b1, dinv2, bufA, NNODES, D_IN, D_H);
    // quantize: bufA(f32,256) -> bufB (q256) + qs
    k_quant<256, false><<<AGB, 256, 0, stream>>>((const float*)bufA, nullptr, (short*)bufB, qs, NNODES);
    // conv2 agg: bufB(q256) -> bufA (hl,256)
    k_agg3<256, 0><<<AGB, 256, 0, stream>>>((const short*)bufB, qs, rp2, col2, dinv2, nullptr, bufA, NNODES);
    // conv2 gemm: relu((.)W2+b2) -> bufB (hl,256)
    k_gemm_mfma<true, true, 2><<<dim3(MT, D_H / 64), 256, 0, stream>>>(
        (const unsigned short*)bufA, W2h, W2l, b2, nullptr, bufB, NNODES, D_H, D_H);
    // L1: relu((.)L1w+b) -> bufA (hl,128)
    k_gemm_mfma<true, true, 2><<<dim3(MT, D_IN / 64), 256, 0, stream>>>(
        (const unsigned short*)bufB, L1h, L1l, L1b, nullptr, bufA, NNODES, D_H, D_IN);
    // L2: relu((.)L2w+b) -> bufB (hl,256)
    k_gemm_mfma<true, true, 2><<<dim3(MT, D_H / 64), 256, 0, stream>>>(
        (const unsigned short*)bufA, L2h, L2l, L2b, nullptr, bufB, NNODES, D_IN, D_H);
    // conv3 gemm: ((.)W3) * dinv2 -> bufA (f32,64)
    k_gemm_mfma<false, false, 1><<<dim3(MT, D_OUT / 64), 256, 0, stream>>>(
        (const unsigned short*)bufB, W3h, W3l, nullptr, dinv2, bufA, NNODES, D_H, D_OUT);
    // quantize: bufA(f32,64) -> bufB (q64) + qs
    k_quant<64, false><<<AGB, 256, 0, stream>>>((const float*)bufA, nullptr, (short*)bufB, qs, NNODES);
    // conv3 agg: bufB(q64) -> out (f32 + b3)
    k_agg3<64, 1><<<AGB, 256, 0, stream>>>((const short*)bufB, qs, rp2, col2, dinv2, b3, out, NNODES);
    // optional softmax (mode != 1)
    k_softmax<<<AGB, 256, 0, stream>>>(out, mode, NNODES);
}